// Round 6
// baseline (136.154 us; speedup 1.0000x reference)
//
#include <hip/hip_runtime.h>

#define BATCH 4
#define VOX 1638400            // 64*160*160
#define VOX4 (VOX / 4)         // 409600 float4-groups per sample
#define BX 320                 // blocks per sample
#define THREADS 256
#define ITERS 5                // 320*256*5 == 409600 exactly
#define NACC 17                // A, P[1..8], N[1..8]
#define NTOT (NACC * BATCH)    // 68

typedef float  vf4 __attribute__((ext_vector_type(4)));
typedef int    vi4 __attribute__((ext_vector_type(4)));

__device__ __forceinline__ float p0_of(float d) {
    // softmax class0 of 2 classes: p0 = 1/(1+exp(x1-x0)); d = x1-x0
    float e = __expf(d);
    return __builtin_amdgcn_rcpf(1.0f + e);   // ~1ulp; threshold is 1e-2
}

// ---------------------------------------------------------------------------
// Kernel 1 (R5 structure + NONTEMPORAL loads). k1 has been ~35 us across all
// body variants (R1/R3/R5) at 2.2 TB/s effective with every pipe idle ->
// per-CU L1 miss-queue bound hypothesis; nt loads bypass L1.
// partials layout: [(j*BATCH + b) * BX + bx], j in [0,17)
// ---------------------------------------------------------------------------
__global__ __launch_bounds__(THREADS, 4) void blob_reduce_kernel(
    const float* __restrict__ x, const int* __restrict__ ml,
    float* __restrict__ partials)
{
    const int b  = blockIdx.y;
    const int bx = blockIdx.x;
    const int t  = threadIdx.x;
    const vf4* __restrict__ x0v = (const vf4*)(x + (size_t)b * 2 * VOX);
    const vf4* __restrict__ x1v = (const vf4*)(x + (size_t)b * 2 * VOX + VOX);
    const vi4* __restrict__ mlv = (const vi4*)(ml + (size_t)b * VOX);

    const int base = bx * (THREADS * ITERS) + t;

    // ---- issue all loads first (nontemporal: bypass L1) ----
    vf4 a0[ITERS], a1[ITERS];
    vi4 mm[ITERS];
#pragma unroll
    for (int k = 0; k < ITERS; ++k) {
        const int i = base + k * THREADS;
        a0[k] = __builtin_nontemporal_load(&x0v[i]);
        a1[k] = __builtin_nontemporal_load(&x1v[i]);
        mm[k] = __builtin_nontemporal_load(&mlv[i]);
    }

    float accA = 0.f;
    float accP[8], accN[8];
#pragma unroll
    for (int k = 0; k < 8; ++k) { accP[k] = 0.f; accN[k] = 0.f; }

#pragma unroll
    for (int k = 0; k < ITERS; ++k) {
        const vi4 m = mm[k];
        float p0 = p0_of(a1[k].x - a0[k].x);
        float p1 = p0_of(a1[k].y - a0[k].y);
        float p2 = p0_of(a1[k].z - a0[k].z);
        float p3 = p0_of(a1[k].w - a0[k].w);
        int orl = m.x | m.y | m.z | m.w;
        if (__ballot(orl != 0) == 0ull) {
            accA += (p0 + p1) + (p2 + p3);      // pure-background wave
        } else {
            accA += (m.x == 0 ? p0 : 0.f) + (m.y == 0 ? p1 : 0.f) +
                    (m.z == 0 ? p2 : 0.f) + (m.w == 0 ? p3 : 0.f);
#pragma unroll
            for (int l = 1; l <= 8; ++l) {
                accP[l - 1] += (m.x == l ? p0 : 0.f) + (m.y == l ? p1 : 0.f) +
                               (m.z == l ? p2 : 0.f) + (m.w == l ? p3 : 0.f);
                accN[l - 1] += (m.x == l ? 1.f : 0.f) + (m.y == l ? 1.f : 0.f) +
                               (m.z == l ? 1.f : 0.f) + (m.w == l ? 1.f : 0.f);
            }
        }
    }

    float accs[NACC];
    accs[0] = accA;
#pragma unroll
    for (int k = 0; k < 8; ++k) { accs[1 + k] = accP[k]; accs[9 + k] = accN[k]; }

    // ---- block reduce: wave shuffle (64 lanes) -> LDS across 4 waves ----
    __shared__ float red[4][NACC];
    const int lane = threadIdx.x & 63;
    const int wave = threadIdx.x >> 6;
#pragma unroll
    for (int j = 0; j < NACC; ++j) {
        float v = accs[j];
        for (int off = 32; off > 0; off >>= 1) v += __shfl_down(v, off, 64);
        if (lane == 0) red[wave][j] = v;
    }
    __syncthreads();
    if (threadIdx.x < NACC) {
        float s = red[0][threadIdx.x] + red[1][threadIdx.x] +
                  red[2][threadIdx.x] + red[3][threadIdx.x];
        partials[((size_t)threadIdx.x * BATCH + b) * BX + bx] = s;
    }
}

// ---------------------------------------------------------------------------
// Kernel 2: reduce 320 partials per (j,b) in double, closed-form loss.
// ---------------------------------------------------------------------------
__global__ __launch_bounds__(256) void blob_finalize_kernel(
    const float* __restrict__ partials, float* __restrict__ out)
{
    __shared__ double totals[NTOT];   // index p = j*BATCH + b
    const int lane = threadIdx.x & 63;
    const int wave = threadIdx.x >> 6;        // 4 waves

    for (int p = wave; p < NTOT; p += 4) {
        double s = 0.0;
#pragma unroll
        for (int i = 0; i < BX / 64; ++i)
            s += (double)partials[(size_t)p * BX + lane + i * 64];
        for (int off = 32; off > 0; off >>= 1) s += __shfl_down(s, off, 64);
        if (lane == 0) totals[p] = s;
    }
    __syncthreads();

    if (threadIdx.x == 0) {
        const double Vd = (double)VOX;
        const double TA = 0.3, TB = 0.7;
        double sum_main = 0.0, sum_blob = 0.0;
        for (int bb = 0; bb < BATCH; ++bb) {
            double A = totals[0 * BATCH + bb];
            double P[8], N[8], SP = 0.0, SN = 0.0;
            for (int k = 0; k < 8; ++k) {
                P[k] = totals[(1 + k) * BATCH + bb];
                N[k] = totals[(9 + k) * BATCH + bb];
                SP += P[k]; SN += N[k];
            }
            double n0 = Vd - SN;
            { // main, class 0 (g = background)
                double tp = A, fp = SP, fn = n0 - A;
                sum_main += tp / fmax(tp + TA * fp + TB * fn, 1e-8);
            }
            { // main, class 1 (g = foreground)
                double tp = SN - SP, fp = n0 - A, fn = SP;
                sum_main += tp / fmax(tp + TA * fp + TB * fn, 1e-8);
            }
            for (int k = 0; k < 8; ++k) {
                double mo = SN - N[k];           // other-blob voxels -> p=(.5,.5)
                { // class 0: g = (L != lab)
                    double tp = A + 0.5 * mo;
                    double fp = P[k];
                    double fn = (Vd - N[k]) - tp;
                    sum_blob += tp / fmax(tp + TA * fp + TB * fn, 1e-8);
                }
                { // class 1: g = (L == lab)
                    double tp = N[k] - P[k];
                    double fp = (n0 - A) + 0.5 * mo;
                    double fn = P[k];
                    sum_blob += tp / fmax(tp + TA * fp + TB * fn, 1e-8);
                }
            }
        }
        out[0] = (float)(-(sum_main / 8.0 + sum_blob / 128.0));
    }
}

extern "C" void kernel_launch(void* const* d_in, const int* in_sizes, int n_in,
                              void* d_out, int out_size, void* d_ws, size_t ws_size,
                              hipStream_t stream) {
    const float* x  = (const float*)d_in[0];
    const int*   ml = (const int*)d_in[1];
    float* out      = (float*)d_out;
    float* partials = (float*)d_ws;   // NTOT*320 floats = 87 KiB

    dim3 grid(BX, BATCH);
    // PROBE: kernel1 launched TWICE (redundant, identical output; WAW on
    // partials keeps them stream-ordered). Bench total = floor(74) +
    // 2*k1 + k2 + gaps -> measures k1 despite top-5 hiding it.
    blob_reduce_kernel<<<grid, THREADS, 0, stream>>>(x, ml, partials);
    blob_reduce_kernel<<<grid, THREADS, 0, stream>>>(x, ml, partials);
    blob_finalize_kernel<<<1, 256, 0, stream>>>(partials, out);
}